// Round 4
// baseline (115.702 us; speedup 1.0000x reference)
//
#include <hip/hip_runtime.h>
#include <stdint.h>

// BinaryTreeLogicNet: out = sigmoid(tree_gcd(sigmoid(x @ W^T - 2)) * w_out + b_out)
// M=65536 rows, L=256 leaves.
// R4: single fused kernel, 32 rows/wave.
//   - Each block stages full W (fp32 global -> bf16 LDS, nibble-swap rows,
//     stride 264) itself; W is L2/L3-resident so staging ~2-5 us. No pre-kernel,
//     no d_ws use. ONE barrier.
//   - 512 thr = 8 waves, 1 block/CU (139 KB LDS), 32 rows/wave: TWO A-fragments
//     share every B ds_read -> per-CU LDS traffic halves vs R3 (2 MB -> 1 MB).
//     DS was the largest modeled pipe term; this is the direct attack.
//   - __launch_bounds__(512,2): 256-VGPR budget; acc=128 + prefetch ~32 -> ~190.
// Tree epilogue: levels 1-4 register-local per lane (nibble-swap gives each
// lane a contiguous 16-leaf subtree), levels 5-8 shfl_xor butterfly.

#define EPS 1e-6f
#define LOG2E 1.44269504088896340736f
#define WSTR 264                 // shorts per W row (256 + 8 pad): uniform 2-way banks
#define WIMG_SHORTS (256 * WSTR)

typedef __attribute__((ext_vector_type(8))) short short8;
typedef __attribute__((ext_vector_type(4))) short short4_t;
typedef __attribute__((ext_vector_type(4))) float float4_t;

__device__ __forceinline__ float fast_sigmoid(float z) {
    float e = __builtin_amdgcn_exp2f(-z * LOG2E);
    return __builtin_amdgcn_rcpf(1.0f + e);
}

__device__ __forceinline__ short f2bf(float f) {   // fp32 -> bf16 RNE
    uint32_t u = __builtin_bit_cast(uint32_t, f);
    u += 0x7FFFu + ((u >> 16) & 1u);
    return (short)(u >> 16);
}

__device__ __forceinline__ float ggcd(float l, float r, float lam) {
    float a = fabsf(l) + EPS;
    float b = fabsf(r) + EPS;
    float mn = fminf(a, b);
    float mx = fmaxf(a, b);
    return fmaf(lam, mn - mx, mx);   // lam*mn + (1-lam)*mx
}

// tree levels 1-4 on one 16-acc row-group; acc consumed in place
__device__ __forceinline__ void tree_reduce(float4_t acc[16], int c0,
                                            const float4* pv, float res[4]) {
    #pragma unroll
    for (int t = 0; t < 16; ++t) {
        #pragma unroll
        for (int r = 0; r < 4; ++r) acc[t][r] = fast_sigmoid(acc[t][r] - 2.0f);
    }
    #pragma unroll
    for (int tp = 0; tp < 8; ++tp) {          // level 1 (off 0)
        float4 p = pv[c0 * 8 + tp];
        #pragma unroll
        for (int r = 0; r < 4; ++r)
            acc[tp][r] = ggcd(acc[2*tp][r] * p.x, acc[2*tp+1][r] * p.y, p.z);
    }
    #pragma unroll
    for (int tp = 0; tp < 4; ++tp) {          // level 2 (off 128)
        float4 p = pv[128 + c0 * 4 + tp];
        #pragma unroll
        for (int r = 0; r < 4; ++r)
            acc[tp][r] = ggcd(acc[2*tp][r] * p.x, acc[2*tp+1][r] * p.y, p.z);
    }
    #pragma unroll
    for (int tp = 0; tp < 2; ++tp) {          // level 3 (off 192)
        float4 p = pv[192 + c0 * 2 + tp];
        #pragma unroll
        for (int r = 0; r < 4; ++r)
            acc[tp][r] = ggcd(acc[2*tp][r] * p.x, acc[2*tp+1][r] * p.y, p.z);
    }
    {                                          // level 4 (off 224)
        float4 p = pv[224 + c0];
        #pragma unroll
        for (int r = 0; r < 4; ++r)
            res[r] = ggcd(acc[0][r] * p.x, acc[1][r] * p.y, p.z);
    }
}

__global__ __launch_bounds__(512, 2)
void btln_fused(const float* __restrict__ x, const float* __restrict__ Wl,
                const float* __restrict__ wts, const float* __restrict__ bia,
                const float* __restrict__ wout, const float* __restrict__ bout,
                float* __restrict__ out) {
    __shared__ short Ws[WIMG_SHORTS];        // 135168 B
    __shared__ float4 pv[256];               // 4096 B (w0,w1,lam)

    const int tid  = threadIdx.x;
    const int lane = tid & 63;
    const int wv   = tid >> 6;               // wave 0..7
    const int c0   = lane & 15;
    const int q    = lane >> 4;

    // ---- stage W: fp32 -> bf16, nibble-swap row permute ----
    {
        const float4* Wv4 = (const float4*)Wl;
        #pragma unroll 4
        for (int it = 0; it < 32; ++it) {
            int i   = it * 512 + tid;         // float4 index 0..16383 (= j*64+kc4)
            int j   = i >> 6;
            int kc4 = i & 63;
            float4 w4 = Wv4[i];
            int p = ((j & 15) << 4) | (j >> 4);
            short4_t s4;
            s4.x = f2bf(w4.x); s4.y = f2bf(w4.y); s4.z = f2bf(w4.z); s4.w = f2bf(w4.w);
            *(short4_t*)&Ws[p * WSTR + kc4 * 4] = s4;
        }
    }
    if (tid < 255)
        pv[tid] = make_float4(wts[2 * tid], wts[2 * tid + 1], fast_sigmoid(bia[tid]), 0.f);
    __syncthreads();                          // the ONLY barrier

    // ---- GEMM: each wave owns 32 rows (two 16-row groups share B reads) ----
    const int rowbase = blockIdx.x * 256 + wv * 32;
    const float4* xv0 = (const float4*)(x + (size_t)(rowbase + c0) * 256);
    const float4* xv1 = (const float4*)(x + (size_t)(rowbase + 16 + c0) * 256);

    float4_t acc0[16], acc1[16];
    #pragma unroll
    for (int t = 0; t < 16; ++t) {
        acc0[t] = (float4_t){0.f, 0.f, 0.f, 0.f};
        acc1[t] = (float4_t){0.f, 0.f, 0.f, 0.f};
    }

    float4 a00 = xv0[q * 2], a01 = xv0[q * 2 + 1];
    float4 a10 = xv1[q * 2], a11 = xv1[q * 2 + 1];
    #pragma unroll 1
    for (int kt = 0; kt < 8; ++kt) {
        const int ktn = (kt < 7) ? kt + 1 : 7;
        float4 n00 = xv0[ktn * 8 + q * 2], n01 = xv0[ktn * 8 + q * 2 + 1];
        float4 n10 = xv1[ktn * 8 + q * 2], n11 = xv1[ktn * 8 + q * 2 + 1];

        short8 af0, af1;
        af0[0] = f2bf(a00.x); af0[1] = f2bf(a00.y); af0[2] = f2bf(a00.z); af0[3] = f2bf(a00.w);
        af0[4] = f2bf(a01.x); af0[5] = f2bf(a01.y); af0[6] = f2bf(a01.z); af0[7] = f2bf(a01.w);
        af1[0] = f2bf(a10.x); af1[1] = f2bf(a10.y); af1[2] = f2bf(a10.z); af1[3] = f2bf(a10.w);
        af1[4] = f2bf(a11.x); af1[5] = f2bf(a11.y); af1[6] = f2bf(a11.z); af1[7] = f2bf(a11.w);

        const int kk = kt * 32;
        #pragma unroll
        for (int t = 0; t < 16; ++t) {
            short8 bf = *(const short8*)&Ws[(t * 16 + c0) * WSTR + kk + q * 8];
            acc0[t] = __builtin_amdgcn_mfma_f32_16x16x32_bf16(af0, bf, acc0[t], 0, 0, 0);
            acc1[t] = __builtin_amdgcn_mfma_f32_16x16x32_bf16(af1, bf, acc1[t], 0, 0, 0);
        }
        a00 = n00; a01 = n01; a10 = n10; a11 = n11;
    }

    // ---- epilogue ----
    float res0[4], res1[4];
    tree_reduce(acc0, c0, pv, res0);
    tree_reduce(acc1, c0, pv, res1);

    const int offs[4] = {240, 248, 252, 254};
    #pragma unroll
    for (int k = 0; k < 4; ++k) {
        float4 p = pv[offs[k] + (c0 >> (k + 1))];
        bool isLeft = ((c0 >> k) & 1) == 0;
        #pragma unroll
        for (int r = 0; r < 4; ++r) {
            float o0 = __shfl_xor(res0[r], 1 << k, 64);
            float o1 = __shfl_xor(res1[r], 1 << k, 64);
            float lf0 = isLeft ? res0[r] : o0, rt0 = isLeft ? o0 : res0[r];
            float lf1 = isLeft ? res1[r] : o1, rt1 = isLeft ? o1 : res1[r];
            res0[r] = ggcd(lf0 * p.x, rt0 * p.y, p.z);
            res1[r] = ggcd(lf1 * p.x, rt1 * p.y, p.z);
        }
    }

    if (c0 == 0) {
        const float wo = wout[0];
        const float bo = bout[0];
        #pragma unroll
        for (int r = 0; r < 4; ++r) {
            out[rowbase + q * 4 + r]      = fast_sigmoid(fmaf(res0[r], wo, bo));
            out[rowbase + 16 + q * 4 + r] = fast_sigmoid(fmaf(res1[r], wo, bo));
        }
    }
}

extern "C" void kernel_launch(void* const* d_in, const int* in_sizes, int n_in,
                              void* d_out, int out_size, void* d_ws, size_t ws_size,
                              hipStream_t stream) {
    const float* x   = (const float*)d_in[0];
    const float* Wl  = (const float*)d_in[1];
    const float* wts = (const float*)d_in[2];
    const float* bia = (const float*)d_in[3];
    const float* wo  = (const float*)d_in[4];
    const float* bo  = (const float*)d_in[5];
    float* out = (float*)d_out;

    const int rows = out_size;               // 65536
    dim3 grid(rows / 256), block(512);       // 256 blocks x 8 waves, 1 block/CU
    btln_fused<<<grid, block, 0, stream>>>(x, Wl, wts, bia, wo, bo, out);
}